// Round 1
// baseline (752.092 us; speedup 1.0000x reference)
//
#include <hip/hip_runtime.h>

typedef __bf16 bf16;
typedef bf16 bf16x8 __attribute__((ext_vector_type(8)));
typedef bf16 bf16x4 __attribute__((ext_vector_type(4)));
typedef float f32x4 __attribute__((ext_vector_type(4)));

constexpr int NN = 8192;   // nodes
constexpr int DD = 512;    // gnn dim

// ---- workspace layout (bytes) ----
constexpr size_t OFF_X    = 0;                       // x f32      [8192][512]  16 MB
constexpr size_t OFF_XB   = 16777216;                // xb bf16    [8192][512]   8 MB
constexpr size_t OFF_XBT  = OFF_XB   + 8388608;      // xbT bf16   [512][8192]   8 MB
constexpr size_t OFF_ACCB = OFF_XBT  + 8388608;      // accb bf16  [8192][512]   8 MB
constexpr size_t OFF_WSB  = OFF_ACCB + 8388608;      // Wsb bf16   [512][512]
constexpr size_t OFF_WNB  = OFF_WSB  + 524288;       // Wnb bf16   [512][512]
constexpr size_t OFF_POOL = OFF_WNB  + 524288;       // pooled f32 [512]
constexpr size_t BASE_END = OFF_POOL + 4096;         // = 42995712
constexpr size_t OFF_ADJB = BASE_END;                // adj bf16 [8192][8192] 128 MB (optional)
constexpr size_t NEED_BF  = OFF_ADJB + 134217728;    // = 177213440

static __device__ inline bf16x8 cvt8(const float* __restrict__ p) {
  f32x4 a = *(const f32x4*)p;
  f32x4 b = *(const f32x4*)(p + 4);
  bf16x8 r;
  r[0] = (bf16)a[0]; r[1] = (bf16)a[1]; r[2] = (bf16)a[2]; r[3] = (bf16)a[3];
  r[4] = (bf16)b[0]; r[5] = (bf16)b[1]; r[6] = (bf16)b[2]; r[7] = (bf16)b[3];
  return r;
}

// async global->LDS, 16B per lane, dest = wave-uniform base + lane*16
#define GLDS(g, l) __builtin_amdgcn_global_load_lds( \
    (const __attribute__((address_space(1))) unsigned int*)(const void*)(g), \
    (__attribute__((address_space(3))) unsigned int*)(void*)(l), 16, 0, 0)

// ---------------- converts ----------------

__global__ __launch_bounds__(256) void convert_w_kernel(
    const float* __restrict__ a, const float* __restrict__ b,
    bf16* __restrict__ ao, bf16* __restrict__ bo) {
  int i8 = ((int)blockIdx.x * 256 + (int)threadIdx.x) * 8;
  if (i8 < DD * DD) {
    *(bf16x8*)&ao[i8] = cvt8(a + i8);
  } else {
    int j = i8 - DD * DD;
    *(bf16x8*)&bo[j] = cvt8(b + j);
  }
}

__global__ __launch_bounds__(256) void convert_adj_kernel(
    const float* __restrict__ a, bf16* __restrict__ o) {
  size_t i8 = ((size_t)blockIdx.x * 256 + threadIdx.x) * 8;
  *(bf16x8*)&o[i8] = cvt8(a + i8);
}

// x f32 [NN][DD] -> xb bf16 [NN][DD] and xbT bf16 [DD][NN] (64x64 LDS tiles)
__global__ __launch_bounds__(256) void convert_x_kernel(
    const float* __restrict__ src, bf16* __restrict__ xb, bf16* __restrict__ xbT) {
  __shared__ __align__(16) float tile[64][68];
  const int tid = (int)threadIdx.x;
  const int r0 = (int)blockIdx.x * 64;
  const int c0 = (int)blockIdx.y * 64;
#pragma unroll
  for (int p = 0; p < 4; ++p) {
    int row = p * 16 + (tid >> 4);
    int col = (tid & 15) * 4;
    *(f32x4*)&tile[row][col] = *(const f32x4*)&src[(size_t)(r0 + row) * DD + c0 + col];
  }
  __syncthreads();
#pragma unroll
  for (int p = 0; p < 4; ++p) {
    int row = p * 16 + (tid >> 4);
    int col = (tid & 15) * 4;
    f32x4 v = *(const f32x4*)&tile[row][col];
    bf16x4 o;
    o[0] = (bf16)v[0]; o[1] = (bf16)v[1]; o[2] = (bf16)v[2]; o[3] = (bf16)v[3];
    *(bf16x4*)&xb[(size_t)(r0 + row) * DD + c0 + col] = o;
  }
  {
    int c = tid >> 2;
    int rp = (tid & 3) * 16;
    bf16x8 o0, o1;
#pragma unroll
    for (int j = 0; j < 8; ++j) o0[j] = (bf16)tile[rp + j][c];
#pragma unroll
    for (int j = 0; j < 8; ++j) o1[j] = (bf16)tile[rp + 8 + j][c];
    *(bf16x8*)&xbT[(size_t)(c0 + c) * NN + r0 + rp] = o0;
    *(bf16x8*)&xbT[(size_t)(c0 + c) * NN + r0 + rp + 8] = o1;
  }
}

// ---------------- GEMM1: accb[NN][DD] = bf16( adj[NN][NN] @ x[NN][DD] ) ----------------
// A = adj (row-major, k contiguous), B = xbT (B^T form [n][k], k contiguous).
// BM=64, BN=128, BK=64; 4 waves (2x2), wave tile 32x64; mfma 16x16x32 bf16.
template<int AF32>
__global__ __launch_bounds__(256)
void gemm1_kernel(const float* __restrict__ adjf, const bf16* __restrict__ adjb,
                  const bf16* __restrict__ xbT, bf16* __restrict__ accb) {
  constexpr int LDA = AF32 ? 80 : 64;  // shorts; pad only on reg-staged path
  __shared__ __align__(16) bf16 lds_a[64 * LDA];
  __shared__ __align__(16) bf16 lds_b[128 * 64];
  const int tid  = (int)threadIdx.x;
  const int lane = tid & 63;
  const int wave = tid >> 6;
  const int wr = wave >> 1;           // 0..1 -> row half (32 rows)
  const int wc = wave & 1;            // 0..1 -> col half (64 cols)
  const int r0 = (int)blockIdx.y * 64;
  const int c0 = (int)blockIdx.x * 128;
  const int fr = lane & 15;
  const int fq = lane >> 4;

  f32x4 acc[2][4] = {};

  for (int kt = 0; kt < NN / 64; ++kt) {
    const int k0 = kt * 64;
    if constexpr (AF32) {
      // reg-stage A: f32 -> bf16, padded LDS
#pragma unroll
      for (int p = 0; p < 2; ++p) {
        int flat = p * 2048 + tid * 8;
        int row = flat >> 6, col = flat & 63;
        bf16x8 v = cvt8(adjf + (size_t)(r0 + row) * NN + k0 + col);
        *(bf16x8*)&lds_a[row * LDA + col] = v;
      }
    } else {
      // direct async stage of pre-converted bf16 adj
#pragma unroll
      for (int c = 0; c < 2; ++c) {
        int chunk = wave * 2 + c;                 // 0..7, 1KB each
        int srow = chunk * 8 + (lane >> 3);
        int scol = (lane & 7) * 8;
        GLDS(adjb + (size_t)(r0 + srow) * NN + k0 + scol, &lds_a[chunk * 512]);
      }
    }
#pragma unroll
    for (int c = 0; c < 4; ++c) {
      int chunk = wave * 4 + c;                   // 0..15, 1KB each
      int srow = chunk * 8 + (lane >> 3);
      int scol = (lane & 7) * 8;
      GLDS(xbT + (size_t)(c0 + srow) * NN + k0 + scol, &lds_b[chunk * 512]);
    }
    __syncthreads();
#pragma unroll
    for (int kk = 0; kk < 2; ++kk) {
      bf16x8 af[2], bv[4];
#pragma unroll
      for (int m = 0; m < 2; ++m)
        af[m] = *(const bf16x8*)&lds_a[(wr * 32 + m * 16 + fr) * LDA + kk * 32 + fq * 8];
#pragma unroll
      for (int n = 0; n < 4; ++n)
        bv[n] = *(const bf16x8*)&lds_b[(wc * 64 + n * 16 + fr) * 64 + kk * 32 + fq * 8];
#pragma unroll
      for (int m = 0; m < 2; ++m)
#pragma unroll
        for (int n = 0; n < 4; ++n)
          acc[m][n] = __builtin_amdgcn_mfma_f32_16x16x32_bf16(af[m], bv[n], acc[m][n], 0, 0, 0);
    }
    __syncthreads();
  }
  // epilogue: C/D layout col=lane&15, row=(lane>>4)*4+reg
#pragma unroll
  for (int m = 0; m < 2; ++m)
#pragma unroll
    for (int n = 0; n < 4; ++n)
#pragma unroll
      for (int r = 0; r < 4; ++r) {
        int row = r0 + wr * 32 + m * 16 + fq * 4 + r;
        int col = c0 + wc * 64 + n * 16 + fr;
        accb[(size_t)row * DD + col] = (bf16)acc[m][n][r];
      }
}

// ---------------- GEMM2: x = relu(xb@Wsb^T + accb@Wnb^T + b_self) ----------------
__global__ __launch_bounds__(256)
void gemm2_kernel(const bf16* __restrict__ xb, const bf16* __restrict__ accb,
                  const bf16* __restrict__ wsb, const bf16* __restrict__ wnb,
                  const float* __restrict__ bself, float* __restrict__ xout) {
  __shared__ __align__(16) bf16 lds_a[64 * 64];
  __shared__ __align__(16) bf16 lds_b[128 * 64];
  const int tid  = (int)threadIdx.x;
  const int lane = tid & 63;
  const int wave = tid >> 6;
  const int wr = wave >> 1;
  const int wc = wave & 1;
  const int r0 = (int)blockIdx.y * 64;
  const int c0 = (int)blockIdx.x * 128;
  const int fr = lane & 15;
  const int fq = lane >> 4;

  f32x4 acc[2][4] = {};

  for (int ph = 0; ph < 2; ++ph) {
    const bf16* __restrict__ A = ph ? accb : xb;
    const bf16* __restrict__ B = ph ? wnb : wsb;
    for (int kt = 0; kt < DD / 64; ++kt) {
      const int k0 = kt * 64;
#pragma unroll
      for (int c = 0; c < 2; ++c) {
        int chunk = wave * 2 + c;
        GLDS(A + (size_t)(r0 + chunk * 8 + (lane >> 3)) * DD + k0 + (lane & 7) * 8,
             &lds_a[chunk * 512]);
      }
#pragma unroll
      for (int c = 0; c < 4; ++c) {
        int chunk = wave * 4 + c;
        GLDS(B + (size_t)(c0 + chunk * 8 + (lane >> 3)) * DD + k0 + (lane & 7) * 8,
             &lds_b[chunk * 512]);
      }
      __syncthreads();
#pragma unroll
      for (int kk = 0; kk < 2; ++kk) {
        bf16x8 af[2], bv[4];
#pragma unroll
        for (int m = 0; m < 2; ++m)
          af[m] = *(const bf16x8*)&lds_a[(wr * 32 + m * 16 + fr) * 64 + kk * 32 + fq * 8];
#pragma unroll
        for (int n = 0; n < 4; ++n)
          bv[n] = *(const bf16x8*)&lds_b[(wc * 64 + n * 16 + fr) * 64 + kk * 32 + fq * 8];
#pragma unroll
        for (int m = 0; m < 2; ++m)
#pragma unroll
          for (int n = 0; n < 4; ++n)
            acc[m][n] = __builtin_amdgcn_mfma_f32_16x16x32_bf16(af[m], bv[n], acc[m][n], 0, 0, 0);
      }
      __syncthreads();
    }
  }
#pragma unroll
  for (int m = 0; m < 2; ++m)
#pragma unroll
    for (int n = 0; n < 4; ++n)
#pragma unroll
      for (int r = 0; r < 4; ++r) {
        int row = r0 + wr * 32 + m * 16 + fq * 4 + r;
        int col = c0 + wc * 64 + n * 16 + fr;
        float v = acc[m][n][r] + bself[col];
        xout[(size_t)row * DD + col] = v > 0.f ? v : 0.f;
      }
}

// ---------------- pooling + head ----------------

__global__ __launch_bounds__(256) void pool_kernel(
    const float* __restrict__ x, float* __restrict__ pooled) {
  const int t = (int)threadIdx.x;
  const int r0 = (int)blockIdx.x * 32;
  float s0 = 0.f, s1 = 0.f;
  for (int r = 0; r < 32; ++r) {
    s0 += x[(size_t)(r0 + r) * DD + t];
    s1 += x[(size_t)(r0 + r) * DD + t + 256];
  }
  atomicAdd(&pooled[t], s0);
  atomicAdd(&pooled[t + 256], s1);
}

__global__ __launch_bounds__(64) void final_kernel(
    const float* __restrict__ pooled, const float* __restrict__ features,
    const float* __restrict__ wfc, const float* __restrict__ bfc,
    float* __restrict__ out) {
  const int t = (int)threadIdx.x;
  float s = 0.f;
  for (int i = t; i < DD + 64; i += 64) {
    float v = (i < DD) ? pooled[i] * (1.0f / (float)NN) : features[i - DD];
    s += v * wfc[i];
  }
#pragma unroll
  for (int off = 32; off > 0; off >>= 1) s += __shfl_down(s, off);
  if (t == 0) {
    float z = s + bfc[0];
    out[0] = 1.0f / (1.0f + expf(-z));
  }
}

// ---------------- launch ----------------

extern "C" void kernel_launch(void* const* d_in, const int* in_sizes, int n_in,
                              void* d_out, int out_size, void* d_ws, size_t ws_size,
                              hipStream_t stream) {
  const float* labels   = (const float*)d_in[0];
  const float* adj      = (const float*)d_in[1];
  const float* features = (const float*)d_in[2];
  const float* W_self   = (const float*)d_in[3];
  const float* b_self   = (const float*)d_in[4];
  const float* W_neigh  = (const float*)d_in[5];
  const float* W_fc     = (const float*)d_in[6];
  const float* b_fc     = (const float*)d_in[7];
  float* out = (float*)d_out;

  char* ws = (char*)d_ws;
  float* x      = (float*)(ws + OFF_X);
  bf16*  xb     = (bf16*)(ws + OFF_XB);
  bf16*  xbT    = (bf16*)(ws + OFF_XBT);
  bf16*  accb   = (bf16*)(ws + OFF_ACCB);
  bf16*  wsb    = (bf16*)(ws + OFF_WSB);
  bf16*  wnb    = (bf16*)(ws + OFF_WNB);
  float* pooled = (float*)(ws + OFF_POOL);
  const bool useBf = (ws_size >= NEED_BF);
  bf16* adjb = useBf ? (bf16*)(ws + OFF_ADJB) : (bf16*)(ws + OFF_ACCB);

  convert_w_kernel<<<(2 * DD * DD / 8 + 255) / 256, 256, 0, stream>>>(W_self, W_neigh, wsb, wnb);
  if (useBf)
    convert_adj_kernel<<<(int)((size_t)NN * NN / 8 / 256), 256, 0, stream>>>(adj, adjb);

  for (int it = 0; it < 4; ++it) {
    convert_x_kernel<<<dim3(NN / 64, DD / 64), 256, 0, stream>>>(it == 0 ? labels : x, xb, xbT);
    if (useBf)
      gemm1_kernel<0><<<dim3(DD / 128, NN / 64), 256, 0, stream>>>(adj, adjb, xbT, accb);
    else
      gemm1_kernel<1><<<dim3(DD / 128, NN / 64), 256, 0, stream>>>(adj, adjb, xbT, accb);
    gemm2_kernel<<<dim3(DD / 128, NN / 64), 256, 0, stream>>>(xb, accb, wsb, wnb, b_self, x);
  }

  hipMemsetAsync(pooled, 0, DD * sizeof(float), stream);
  pool_kernel<<<NN / 32, 256, 0, stream>>>(x, pooled);
  final_kernel<<<1, 64, 0, stream>>>(pooled, features, W_fc, b_fc, out);
}